// Round 2
// baseline (336.774 us; speedup 1.0000x reference)
//
#include <hip/hip_runtime.h>
#include <hip/hip_cooperative_groups.h>

namespace cg = cooperative_groups;

#define NN 10000
#define KK 64
#define CC 128
#define OUTOFF (NN * CC)
#define NA 256        // grid size == split-K blocks for phase A
#define CHUNKS_A 625  // 625 * 16 == 10000
#define CHUNKS_C 313  // 313 * 32 == 10016 (last chunk partially masked)

__device__ __forceinline__ float4 f4fma(float s, float4 v, float4 a) {
    a.x = fmaf(s, v.x, a.x); a.y = fmaf(s, v.y, a.y);
    a.z = fmaf(s, v.z, a.z); a.w = fmaf(s, v.w, a.w);
    return a;
}

// ws layout (floats): [0 .. NA*16384)            phase-A partials (U|V per block)
//                     [NA*16384 .. +16384)        UV   (reduced)
//                     [NA*16384+16384 .. +16384)  UVW  (diag(TT)*(U|V)@W)
// total 16.9 MB << ws_size (~268 MB per poison-fill evidence)
__global__ __launch_bounds__(512, 1) void fused(
    const float* __restrict__ re, const float* __restrict__ im,
    const float* __restrict__ Qr, const float* __restrict__ Qi,
    const float* __restrict__ Ritz, const int* __restrict__ ldp,
    const float* __restrict__ W, float* __restrict__ ws,
    float* __restrict__ out)
{
    __shared__ float4 smem[4096];   // 64 KB, reused by every phase
    cg::grid_group grid = cg::this_grid();
    const int t = threadIdx.x;
    const int bid = blockIdx.x;

    // ================= Phase A: partial U,V = Q^T X over 16-row chunks =================
    {
        const int kt = t & 15;        // k0 = 4*kt
        const int ctA = t >> 4;       // c0 = 4*ctA (0..31)
        // staging roles: i0=t -> Qr(t<256)/Qi, i1=t+512 -> re, i2=t+1024 -> im
        const int row_q = (t & 255) >> 4, q_q = t & 15;
        const int row_x = t >> 5,          q_x = t & 31;   // t<512 so row_x 0..15
        const float4* gq  = (const float4*)((t < 256) ? Qr : Qi);
        const float4* gre = (const float4*)re;
        const float4* gim = (const float4*)im;

        float aU[4][4] = {}, aV[4][4] = {};

        int cb = bid;
        int n0 = cb * 16;
        float4 r0 = gq [(size_t)(n0 + row_q) * 16 + q_q];
        float4 r1 = gre[(size_t)(n0 + row_x) * 32 + q_x];
        float4 r2 = gim[(size_t)(n0 + row_x) * 32 + q_x];

        while (true) {
            smem[t] = r0; smem[512 + t] = r1; smem[1024 + t] = r2;
            __syncthreads();
            const int nx = cb + NA;
            if (nx < CHUNKS_A) {   // prefetch next chunk while computing this one
                const int m0 = nx * 16;
                r0 = gq [(size_t)(m0 + row_q) * 16 + q_q];
                r1 = gre[(size_t)(m0 + row_x) * 32 + q_x];
                r2 = gim[(size_t)(m0 + row_x) * 32 + q_x];
            }
#pragma unroll 4
            for (int rr = 0; rr < 16; ++rr) {
                float4 q_r = smem[rr * 16 + kt];
                float4 q_i = smem[256 + rr * 16 + kt];
                float4 x_r = smem[512 + rr * 32 + ctA];
                float4 x_i = smem[1024 + rr * 32 + ctA];
                float qr_[4] = {q_r.x, q_r.y, q_r.z, q_r.w};
                float qi_[4] = {q_i.x, q_i.y, q_i.z, q_i.w};
                float xr_[4] = {x_r.x, x_r.y, x_r.z, x_r.w};
                float xi_[4] = {x_i.x, x_i.y, x_i.z, x_i.w};
#pragma unroll
                for (int a = 0; a < 4; ++a)
#pragma unroll
                    for (int b = 0; b < 4; ++b) {
                        aU[a][b] = fmaf(qr_[a], xr_[b], aU[a][b]);
                        aU[a][b] = fmaf(qi_[a], xi_[b], aU[a][b]);
                        aV[a][b] = fmaf(qi_[a], xr_[b], aV[a][b]);
                        aV[a][b] = fmaf(-qr_[a], xi_[b], aV[a][b]);
                    }
            }
            __syncthreads();
            if (nx >= CHUNKS_A) break;
            cb = nx;
        }
        float* base = ws + (size_t)bid * 16384;
        const int k0 = kt * 4, c0 = ctA * 4;
#pragma unroll
        for (int a = 0; a < 4; ++a) {
            *(float4*)(base + (k0 + a) * CC + c0)        = make_float4(aU[a][0], aU[a][1], aU[a][2], aU[a][3]);
            *(float4*)(base + 8192 + (k0 + a) * CC + c0) = make_float4(aV[a][0], aV[a][1], aV[a][2], aV[a][3]);
        }
    }
    __threadfence();
    grid.sync();

    // ================= Phase R: reduce 256 partials -> UV (all 256 blocks) =================
    {
        const int ei = t & 63, sl = t >> 6;
        float s = 0.f;
        const float* p = ws + (size_t)sl * 16384 + bid * 64 + ei;
        for (int b = sl; b < NA; b += 8) { s += *p; p += (size_t)8 * 16384; }
        float* sf = (float*)smem;
        sf[t] = s;
        __syncthreads();
        if (t < 64) {
            float tot = 0.f;
#pragma unroll
            for (int q = 0; q < 8; ++q) tot += sf[q * 64 + t];
            ws[(size_t)NA * 16384 + bid * 64 + t] = tot;
        }
        __syncthreads();
    }
    __threadfence();
    grid.sync();

    // ================= Phase B: UVW = diag(TT) * (U|V) @ W (blocks 0..63) =================
    if (bid < KK) {
        const float* UV = ws + (size_t)NA * 16384;
        float* sf = (float*)smem;
        if (t < 256) sf[t] = (t < 128) ? UV[bid * 128 + t]
                                       : UV[8192 + bid * 128 + (t - 128)];
        __syncthreads();
        if (t < 256) {
            const int m = t >> 7, c = t & 127;
            const float* rowm = sf + m * 128;
            float acc = 0.f;
#pragma unroll 8
            for (int cp = 0; cp < 128; ++cp)
                acc = fmaf(rowm[cp], W[cp * 128 + c], acc);
            const int ld = *ldp;
            const float rz = Ritz[bid];
            float tt = 1.f;
            for (int i = 0; i < ld; ++i) tt *= rz;
            ws[(size_t)NA * 16384 + 16384 + m * 8192 + bid * 128 + c] = tt * acc;
        }
        __syncthreads();
    }
    __threadfence();
    grid.sync();

    // ================= Phase C: res = Q @ UVW + masked-ReLU epilogue =================
    {
        const float4* gUVW = (const float4*)(ws + (size_t)NA * 16384 + 16384);
        for (int i = t; i < 4096; i += 512) smem[i] = gUVW[i];
        __syncthreads();
        // smem[k*32+q] = UW (m=0), smem[2048 + k*32+q] = VW (m=1); q = float4 col idx
        const int ct = t & 15;     // cols 4*ct..+3 and 64+4*ct..+3
        const int r  = t >> 4;     // row within 32-row chunk (0..31)

        for (int cb = bid; cb < CHUNKS_C; cb += NA) {
            const int na = cb * 32 + r;
            if (na >= NN) continue;
            const float4* qr4 = (const float4*)(Qr + (size_t)na * KK);
            const float4* qi4 = (const float4*)(Qi + (size_t)na * KK);
            float4 z = make_float4(0.f, 0.f, 0.f, 0.f);
            float4 aR0 = z, aR1 = z, aI0 = z, aI1 = z;
#pragma unroll 4
            for (int k4 = 0; k4 < 16; ++k4) {
                float4 QR = qr4[k4], QI = qi4[k4];
                float ar[4] = {QR.x, QR.y, QR.z, QR.w};
                float ai[4] = {QI.x, QI.y, QI.z, QI.w};
#pragma unroll
                for (int j = 0; j < 4; ++j) {
                    const int k = k4 * 4 + j;
                    float4 uw0 = smem[k * 32 + ct];
                    float4 uw1 = smem[k * 32 + 16 + ct];
                    float4 vw0 = smem[2048 + k * 32 + ct];
                    float4 vw1 = smem[2048 + k * 32 + 16 + ct];
                    aR0 = f4fma(ar[j], uw0, aR0); aR0 = f4fma(ai[j], vw0, aR0);
                    aR1 = f4fma(ar[j], uw1, aR1); aR1 = f4fma(ai[j], vw1, aR1);
                    aI0 = f4fma(ai[j], uw0, aI0); aI0 = f4fma(-ar[j], vw0, aI0);
                    aI1 = f4fma(ai[j], uw1, aI1); aI1 = f4fma(-ar[j], vw1, aI1);
                }
            }
            const int c0 = ct * 4;
#pragma unroll
            for (int half = 0; half < 2; ++half) {
                const int cc = c0 + half * 64;
                const float4 aR = half ? aR1 : aR0;
                const float4 aI = half ? aI1 : aI0;
                float4 rin = *(const float4*)(re + (size_t)na * CC + cc);
                float4 iin = *(const float4*)(im + (size_t)na * CC + cc);
                float4 orr, oii;
                orr.x = rin.x + (aR.x >= 0.f ? aR.x : 0.f); oii.x = iin.x + (aR.x >= 0.f ? aI.x : 0.f);
                orr.y = rin.y + (aR.y >= 0.f ? aR.y : 0.f); oii.y = iin.y + (aR.y >= 0.f ? aI.y : 0.f);
                orr.z = rin.z + (aR.z >= 0.f ? aR.z : 0.f); oii.z = iin.z + (aR.z >= 0.f ? aI.z : 0.f);
                orr.w = rin.w + (aR.w >= 0.f ? aR.w : 0.f); oii.w = iin.w + (aR.w >= 0.f ? aI.w : 0.f);
                *(float4*)(out + (size_t)na * CC + cc)          = orr;
                *(float4*)(out + OUTOFF + (size_t)na * CC + cc) = oii;
            }
        }
    }
}

extern "C" void kernel_launch(void* const* d_in, const int* in_sizes, int n_in,
                              void* d_out, int out_size, void* d_ws, size_t ws_size,
                              hipStream_t stream) {
    const float* re   = (const float*)d_in[0];
    const float* im   = (const float*)d_in[1];
    const float* Qr   = (const float*)d_in[2];
    const float* Qi   = (const float*)d_in[3];
    const float* Ritz = (const float*)d_in[4];
    const float* W    = (const float*)d_in[5];
    const int*   ldp  = (const int*)d_in[6];
    float* out = (float*)d_out;
    float* ws  = (float*)d_ws;

    void* args[] = { (void*)&re, (void*)&im, (void*)&Qr, (void*)&Qi,
                     (void*)&Ritz, (void*)&ldp, (void*)&W, (void*)&ws, (void*)&out };
    hipLaunchCooperativeKernel((void*)fused, dim3(NA), dim3(512), args, 0, stream);
}

// Round 3
// 121.743 us; speedup vs baseline: 2.7663x; 2.7663x over previous
//
#include <hip/hip_runtime.h>

#define NN 10000
#define KK 64
#define CC 128
#define OUTOFF (NN * CC)
#define NA 256        // split-K blocks in kA
#define CHUNKS_A 625  // 625 * 16 == 10000
#define CHUNKS_C 313  // 313 * 32 == 10016 (tail rows masked)

__device__ __forceinline__ float4 f4fma(float s, float4 v, float4 a) {
    a.x = fmaf(s, v.x, a.x); a.y = fmaf(s, v.y, a.y);
    a.z = fmaf(s, v.z, a.z); a.w = fmaf(s, v.w, a.w);
    return a;
}

// ws layout (floats): [0 .. NA*16384)  partials [b][m][k][c]   (16.8 MB)
//                     [NA*16384 .. +16384)  UVW [m][k][c]      (64 KB)

// ---------------- kA: partial U,V = split-K of Q^T X (prefetch-pipelined) ----------------
__global__ __launch_bounds__(512) void kA(const float* __restrict__ re,
                                          const float* __restrict__ im,
                                          const float* __restrict__ Qr,
                                          const float* __restrict__ Qi,
                                          float* __restrict__ part)
{
    __shared__ float4 smem[1536];   // 24 KB: Qr 256 | Qi 256 | re 512 | im 512
    const int t = threadIdx.x;
    const int bid = blockIdx.x;
    const int kt = t & 15;        // k0 = 4*kt
    const int ctA = t >> 4;       // c0 = 4*ctA (0..31)
    const int row_q = (t & 255) >> 4, q_q = t & 15;
    const int row_x = t >> 5,          q_x = t & 31;
    const float4* gq  = (const float4*)((t < 256) ? Qr : Qi);   // wave-uniform select
    const float4* gre = (const float4*)re;
    const float4* gim = (const float4*)im;

    float aU[4][4] = {}, aV[4][4] = {};

    int cb = bid;
    float4 r0 = gq [(size_t)(cb * 16 + row_q) * 16 + q_q];
    float4 r1 = gre[(size_t)(cb * 16 + row_x) * 32 + q_x];
    float4 r2 = gim[(size_t)(cb * 16 + row_x) * 32 + q_x];

    while (true) {
        smem[t] = r0; smem[512 + t] = r1; smem[1024 + t] = r2;
        __syncthreads();
        const int nx = cb + NA;
        if (nx < CHUNKS_A) {   // prefetch next chunk into registers during compute
            const int m0 = nx * 16;
            r0 = gq [(size_t)(m0 + row_q) * 16 + q_q];
            r1 = gre[(size_t)(m0 + row_x) * 32 + q_x];
            r2 = gim[(size_t)(m0 + row_x) * 32 + q_x];
        }
#pragma unroll 4
        for (int rr = 0; rr < 16; ++rr) {
            float4 q_r = smem[rr * 16 + kt];
            float4 q_i = smem[256 + rr * 16 + kt];
            float4 x_r = smem[512 + rr * 32 + ctA];
            float4 x_i = smem[1024 + rr * 32 + ctA];
            float qr_[4] = {q_r.x, q_r.y, q_r.z, q_r.w};
            float qi_[4] = {q_i.x, q_i.y, q_i.z, q_i.w};
            float xr_[4] = {x_r.x, x_r.y, x_r.z, x_r.w};
            float xi_[4] = {x_i.x, x_i.y, x_i.z, x_i.w};
#pragma unroll
            for (int a = 0; a < 4; ++a)
#pragma unroll
                for (int b = 0; b < 4; ++b) {
                    aU[a][b] = fmaf(qr_[a], xr_[b], aU[a][b]);
                    aU[a][b] = fmaf(qi_[a], xi_[b], aU[a][b]);
                    aV[a][b] = fmaf(qi_[a], xr_[b], aV[a][b]);
                    aV[a][b] = fmaf(-qr_[a], xi_[b], aV[a][b]);
                }
        }
        __syncthreads();
        if (nx >= CHUNKS_A) break;
        cb = nx;
    }
    float* base = part + (size_t)bid * 16384;
    const int k0 = kt * 4, c0 = ctA * 4;
#pragma unroll
    for (int a = 0; a < 4; ++a) {
        *(float4*)(base + (k0 + a) * CC + c0)        = make_float4(aU[a][0], aU[a][1], aU[a][2], aU[a][3]);
        *(float4*)(base + 8192 + (k0 + a) * CC + c0) = make_float4(aV[a][0], aV[a][1], aV[a][2], aV[a][3]);
    }
}

// ---------------- kRB: reduce 256 partials -> row, then UVW = TT * row @ W ----------------
// grid 128 = (m in {U,V}) x (k in 0..63); 512 threads
__global__ __launch_bounds__(512) void kRB(const float* __restrict__ part,
                                           const float* __restrict__ Ritz,
                                           const int* __restrict__ ldp,
                                           const float* __restrict__ W,
                                           float* __restrict__ UVW)
{
    __shared__ float red[512];
    __shared__ float rowS[128];
    const int t = threadIdx.x;
    const int m = blockIdx.x >> 6, k = blockIdx.x & 63;
    const int c = t & 127, bl = t >> 7;   // 4 independent partial lanes

    // 4 independent accumulator chains, 4 outstanding loads per round
    const float* p = part + (size_t)bl * 16384 + m * 8192 + k * 128 + c;
    float s0 = 0.f, s1 = 0.f, s2 = 0.f, s3 = 0.f;
#pragma unroll 4
    for (int jj = 0; jj < 16; ++jj) {
        s0 += p[0];
        s1 += p[4  * 16384];
        s2 += p[8  * 16384];
        s3 += p[12 * 16384];
        p += 16 * 16384;
    }
    red[t] = s0 + s1 + s2 + s3;
    __syncthreads();
    if (t < 128) rowS[t] = red[t] + red[t + 128] + red[t + 256] + red[t + 384];
    __syncthreads();
    if (t < 128) {
        float acc = 0.f;
#pragma unroll 8
        for (int cp = 0; cp < 128; ++cp)
            acc = fmaf(rowS[cp], W[cp * 128 + t], acc);
        const int ld = *ldp;
        const float rz = Ritz[k];
        float tt = 1.f;
        for (int i = 0; i < ld; ++i) tt *= rz;
        UVW[m * 8192 + k * 128 + t] = tt * acc;
    }
}

// ---------------- kC: res = Q @ UVW + masked-ReLU epilogue (313 blocks, 1 chunk each) ----------------
__global__ __launch_bounds__(256) void kC(const float* __restrict__ re,
                                          const float* __restrict__ im,
                                          const float* __restrict__ Qr,
                                          const float* __restrict__ Qi,
                                          const float* __restrict__ UVW,
                                          float* __restrict__ out)
{
    __shared__ float4 sUW[64][16];   // [k][col-group] cols 0..63 in [0..15]... full 128: 32 groups
    __shared__ float4 sVW[64][16];
    __shared__ float4 sUW1[64][16];
    __shared__ float4 sVW1[64][16];
    const int t = threadIdx.x;
    {
        // UVW: [m][k][c]; split c into two halves for the two col-blocks
        const float4* g = (const float4*)UVW;
        for (int i = t; i < 2048; i += 256) {
            int k = i >> 5, q = i & 31;        // q: float4 col group 0..31
            float4 v = g[i];                   // UW
            if (q < 16) sUW[k][q] = v; else sUW1[k][q - 16] = v;
        }
        for (int i = t; i < 2048; i += 256) {
            int k = i >> 5, q = i & 31;
            float4 v = g[2048 + i];            // VW
            if (q < 16) sVW[k][q] = v; else sVW1[k][q - 16] = v;
        }
    }
    __syncthreads();
    const int ct = t & 15;   // cols 4*ct..+3 and 64+4*ct..+3
    const int rp = t >> 4;   // row pair (0..15) within 32-row chunk

    const int na = blockIdx.x * 32 + rp * 2;
    if (na >= NN) return;    // N%32==16: row pairs all-valid or all-invalid
    const int nb = na + 1;
    const float4* qra = (const float4*)(Qr + (size_t)na * KK);
    const float4* qia = (const float4*)(Qi + (size_t)na * KK);
    const float4* qrb = (const float4*)(Qr + (size_t)nb * KK);
    const float4* qib = (const float4*)(Qi + (size_t)nb * KK);

    float4 z = make_float4(0.f, 0.f, 0.f, 0.f);
    float4 aR0a = z, aR1a = z, aI0a = z, aI1a = z;
    float4 aR0b = z, aR1b = z, aI0b = z, aI1b = z;

#pragma unroll 4
    for (int k4 = 0; k4 < 16; ++k4) {
        float4 QRa = qra[k4], QIa = qia[k4];
        float4 QRb = qrb[k4], QIb = qib[k4];
        float ar[4] = {QRa.x, QRa.y, QRa.z, QRa.w};
        float ai[4] = {QIa.x, QIa.y, QIa.z, QIa.w};
        float br[4] = {QRb.x, QRb.y, QRb.z, QRb.w};
        float bi[4] = {QIb.x, QIb.y, QIb.z, QIb.w};
#pragma unroll
        for (int j = 0; j < 4; ++j) {
            const int k = k4 * 4 + j;
            float4 uw0 = sUW[k][ct],  uw1 = sUW1[k][ct];
            float4 vw0 = sVW[k][ct],  vw1 = sVW1[k][ct];
            aR0a = f4fma(ar[j], uw0, aR0a); aR0a = f4fma(ai[j], vw0, aR0a);
            aR1a = f4fma(ar[j], uw1, aR1a); aR1a = f4fma(ai[j], vw1, aR1a);
            aI0a = f4fma(ai[j], uw0, aI0a); aI0a = f4fma(-ar[j], vw0, aI0a);
            aI1a = f4fma(ai[j], uw1, aI1a); aI1a = f4fma(-ar[j], vw1, aI1a);
            aR0b = f4fma(br[j], uw0, aR0b); aR0b = f4fma(bi[j], vw0, aR0b);
            aR1b = f4fma(br[j], uw1, aR1b); aR1b = f4fma(bi[j], vw1, aR1b);
            aI0b = f4fma(bi[j], uw0, aI0b); aI0b = f4fma(-br[j], vw0, aI0b);
            aI1b = f4fma(bi[j], uw1, aI1b); aI1b = f4fma(-br[j], vw1, aI1b);
        }
    }
    const int c0 = ct * 4;
#pragma unroll
    for (int half = 0; half < 2; ++half) {
        const int cc = c0 + half * 64;
        const float4 aRa = half ? aR1a : aR0a;
        const float4 aIa = half ? aI1a : aI0a;
        const float4 aRb = half ? aR1b : aR0b;
        const float4 aIb = half ? aI1b : aI0b;

        float4 rin = *(const float4*)(re + (size_t)na * CC + cc);
        float4 iin = *(const float4*)(im + (size_t)na * CC + cc);
        float4 orr, oii;
        orr.x = rin.x + (aRa.x >= 0.f ? aRa.x : 0.f); oii.x = iin.x + (aRa.x >= 0.f ? aIa.x : 0.f);
        orr.y = rin.y + (aRa.y >= 0.f ? aRa.y : 0.f); oii.y = iin.y + (aRa.y >= 0.f ? aIa.y : 0.f);
        orr.z = rin.z + (aRa.z >= 0.f ? aRa.z : 0.f); oii.z = iin.z + (aRa.z >= 0.f ? aIa.z : 0.f);
        orr.w = rin.w + (aRa.w >= 0.f ? aRa.w : 0.f); oii.w = iin.w + (aRa.w >= 0.f ? aIa.w : 0.f);
        *(float4*)(out + (size_t)na * CC + cc)          = orr;
        *(float4*)(out + OUTOFF + (size_t)na * CC + cc) = oii;

        rin = *(const float4*)(re + (size_t)nb * CC + cc);
        iin = *(const float4*)(im + (size_t)nb * CC + cc);
        orr.x = rin.x + (aRb.x >= 0.f ? aRb.x : 0.f); oii.x = iin.x + (aRb.x >= 0.f ? aIb.x : 0.f);
        orr.y = rin.y + (aRb.y >= 0.f ? aRb.y : 0.f); oii.y = iin.y + (aRb.y >= 0.f ? aIb.y : 0.f);
        orr.z = rin.z + (aRb.z >= 0.f ? aRb.z : 0.f); oii.z = iin.z + (aRb.z >= 0.f ? aIb.z : 0.f);
        orr.w = rin.w + (aRb.w >= 0.f ? aRb.w : 0.f); oii.w = iin.w + (aRb.w >= 0.f ? aIb.w : 0.f);
        *(float4*)(out + (size_t)nb * CC + cc)          = orr;
        *(float4*)(out + OUTOFF + (size_t)nb * CC + cc) = oii;
    }
}

extern "C" void kernel_launch(void* const* d_in, const int* in_sizes, int n_in,
                              void* d_out, int out_size, void* d_ws, size_t ws_size,
                              hipStream_t stream) {
    const float* re   = (const float*)d_in[0];
    const float* im   = (const float*)d_in[1];
    const float* Qr   = (const float*)d_in[2];
    const float* Qi   = (const float*)d_in[3];
    const float* Ritz = (const float*)d_in[4];
    const float* W    = (const float*)d_in[5];
    const int*   ldp  = (const int*)d_in[6];
    float* out = (float*)d_out;
    float* ws  = (float*)d_ws;

    float* part = ws;                          // NA * 16384 floats
    float* UVW  = ws + (size_t)NA * 16384;     // 16384 floats

    kA <<<NA,       512, 0, stream>>>(re, im, Qr, Qi, part);
    kRB<<<128,      512, 0, stream>>>(part, Ritz, ldp, W, UVW);
    kC <<<CHUNKS_C, 256, 0, stream>>>(re, im, Qr, Qi, UVW, out);
}

// Round 4
// 113.876 us; speedup vs baseline: 2.9574x; 1.0691x over previous
//
#include <hip/hip_runtime.h>

#define NN 10000
#define KK 64
#define CC 128
#define OUTOFF (NN * CC)
#define NA 256        // split-K blocks in kA
#define CHUNKS_A 625  // 625 * 16 == 10000

__device__ __forceinline__ float4 f4fma(float s, float4 v, float4 a) {
    a.x = fmaf(s, v.x, a.x); a.y = fmaf(s, v.y, a.y);
    a.z = fmaf(s, v.z, a.z); a.w = fmaf(s, v.w, a.w);
    return a;
}
__device__ __forceinline__ float4 f4add(float4 a, float4 b) {
    a.x += b.x; a.y += b.y; a.z += b.z; a.w += b.w; return a;
}

// ws layout (floats): [0 .. NA*16384)  partials [b][m][k][c]   (16.8 MB)
//                     [NA*16384 .. +16384)  UVW [m][k][c]      (64 KB)

// ---------------- kA: partial U,V = split-K of Q^T X (prefetch-pipelined) ----------------
__global__ __launch_bounds__(512) void kA(const float* __restrict__ re,
                                          const float* __restrict__ im,
                                          const float* __restrict__ Qr,
                                          const float* __restrict__ Qi,
                                          float* __restrict__ part)
{
    __shared__ float4 smem[1536];   // 24 KB: Qr 256 | Qi 256 | re 512 | im 512
    const int t = threadIdx.x;
    const int bid = blockIdx.x;
    const int kt = t & 15;        // k0 = 4*kt
    const int ctA = t >> 4;       // c0 = 4*ctA (0..31)
    const int row_q = (t & 255) >> 4, q_q = t & 15;
    const int row_x = t >> 5,          q_x = t & 31;
    const float4* gq  = (const float4*)((t < 256) ? Qr : Qi);   // wave-uniform select
    const float4* gre = (const float4*)re;
    const float4* gim = (const float4*)im;

    float aU[4][4] = {}, aV[4][4] = {};

    int cb = bid;
    float4 r0 = gq [(size_t)(cb * 16 + row_q) * 16 + q_q];
    float4 r1 = gre[(size_t)(cb * 16 + row_x) * 32 + q_x];
    float4 r2 = gim[(size_t)(cb * 16 + row_x) * 32 + q_x];

    while (true) {
        smem[t] = r0; smem[512 + t] = r1; smem[1024 + t] = r2;
        __syncthreads();
        const int nx = cb + NA;
        if (nx < CHUNKS_A) {   // prefetch next chunk into registers during compute
            const int m0 = nx * 16;
            r0 = gq [(size_t)(m0 + row_q) * 16 + q_q];
            r1 = gre[(size_t)(m0 + row_x) * 32 + q_x];
            r2 = gim[(size_t)(m0 + row_x) * 32 + q_x];
        }
#pragma unroll 4
        for (int rr = 0; rr < 16; ++rr) {
            float4 q_r = smem[rr * 16 + kt];
            float4 q_i = smem[256 + rr * 16 + kt];
            float4 x_r = smem[512 + rr * 32 + ctA];
            float4 x_i = smem[1024 + rr * 32 + ctA];
            float qr_[4] = {q_r.x, q_r.y, q_r.z, q_r.w};
            float qi_[4] = {q_i.x, q_i.y, q_i.z, q_i.w};
            float xr_[4] = {x_r.x, x_r.y, x_r.z, x_r.w};
            float xi_[4] = {x_i.x, x_i.y, x_i.z, x_i.w};
#pragma unroll
            for (int a = 0; a < 4; ++a)
#pragma unroll
                for (int b = 0; b < 4; ++b) {
                    aU[a][b] = fmaf(qr_[a], xr_[b], aU[a][b]);
                    aU[a][b] = fmaf(qi_[a], xi_[b], aU[a][b]);
                    aV[a][b] = fmaf(qi_[a], xr_[b], aV[a][b]);
                    aV[a][b] = fmaf(-qr_[a], xi_[b], aV[a][b]);
                }
        }
        __syncthreads();
        if (nx >= CHUNKS_A) break;
        cb = nx;
    }
    float* base = part + (size_t)bid * 16384;
    const int k0 = kt * 4, c0 = ctA * 4;
#pragma unroll
    for (int a = 0; a < 4; ++a) {
        *(float4*)(base + (k0 + a) * CC + c0)        = make_float4(aU[a][0], aU[a][1], aU[a][2], aU[a][3]);
        *(float4*)(base + 8192 + (k0 + a) * CC + c0) = make_float4(aV[a][0], aV[a][1], aV[a][2], aV[a][3]);
    }
}

// ---------------- kRB: reduce 256 partials -> row, then UVW = TT * row @ W ----------------
// grid 128 = (m in {U,V}) x (k in 0..63); 256 threads; float4 loads, 4 chains
__global__ __launch_bounds__(256) void kRB(const float* __restrict__ part,
                                           const float* __restrict__ Ritz,
                                           const int* __restrict__ ldp,
                                           const float* __restrict__ W,
                                           float* __restrict__ UVW)
{
    __shared__ float4 red4[256];
    __shared__ float rowS[128];
    const int t = threadIdx.x;
    const int m = blockIdx.x >> 6, k = blockIdx.x & 63;
    const int q = t & 31, sl = t >> 5;   // q: float4 col group, sl: slice lane (0..7)

    // 32 slices per thread in 4 independent chains of 8
    const float4* p = (const float4*)part + (size_t)sl * 4096 + m * 2048 + k * 32 + q;
    float4 z = make_float4(0.f, 0.f, 0.f, 0.f);
    float4 s0 = z, s1 = z, s2 = z, s3 = z;
#pragma unroll 2
    for (int jj = 0; jj < 8; ++jj) {
        s0 = f4add(s0, p[0]);
        s1 = f4add(s1, p[(size_t)8  * 4096]);
        s2 = f4add(s2, p[(size_t)16 * 4096]);
        s3 = f4add(s3, p[(size_t)24 * 4096]);
        p += (size_t)32 * 4096;
    }
    red4[t] = f4add(f4add(s0, s1), f4add(s2, s3));
    __syncthreads();
    if (t < 32) {
        float4 tot = z;
#pragma unroll
        for (int g = 0; g < 8; ++g) tot = f4add(tot, red4[g * 32 + t]);
        ((float4*)rowS)[t] = tot;
    }
    __syncthreads();
    if (t < 128) {
        float acc = 0.f;
#pragma unroll 8
        for (int cp = 0; cp < 128; ++cp)
            acc = fmaf(rowS[cp], W[cp * 128 + t], acc);
        const int ld = *ldp;
        const float rz = Ritz[k];
        float tt = 1.f;
        for (int i = 0; i < ld; ++i) tt *= rz;
        UVW[m * 8192 + k * 128 + t] = tt * acc;
    }
}

// ---------------- kC: res = Q @ UVW + masked-ReLU epilogue ----------------
// 625 blocks x 256 threads, 16 rows/block (exact). Thread = 2 rows x 4 cols.
__global__ __launch_bounds__(256) void kC(const float* __restrict__ re,
                                          const float* __restrict__ im,
                                          const float* __restrict__ Qr,
                                          const float* __restrict__ Qi,
                                          const float* __restrict__ UVW,
                                          float* __restrict__ out)
{
    __shared__ float4 s[4096];   // [0..2047] UW [k][c4], [2048..4095] VW [k][c4]
    const int t = threadIdx.x;
    {
        const float4* g = (const float4*)UVW;
        for (int i = t; i < 4096; i += 256) s[i] = g[i];
    }
    __syncthreads();
    const int ct = t & 31;   // float4 col group: cols 4*ct..+3
    const int r  = t >> 5;   // 0..7
    const int na = blockIdx.x * 16 + r;      // rows na and na+8; 625*16==10000, no mask
    const int nb = na + 8;

    const float4* qra = (const float4*)(Qr + (size_t)na * KK);
    const float4* qia = (const float4*)(Qi + (size_t)na * KK);
    const float4* qrb = (const float4*)(Qr + (size_t)nb * KK);
    const float4* qib = (const float4*)(Qi + (size_t)nb * KK);

    float4 z = make_float4(0.f, 0.f, 0.f, 0.f);
    float4 Ra = z, Ia = z, Rb = z, Ib = z;

#pragma unroll 4
    for (int k4 = 0; k4 < 16; ++k4) {
        float4 QRa = qra[k4], QIa = qia[k4];
        float4 QRb = qrb[k4], QIb = qib[k4];
        float ar[4] = {QRa.x, QRa.y, QRa.z, QRa.w};
        float ai[4] = {QIa.x, QIa.y, QIa.z, QIa.w};
        float br[4] = {QRb.x, QRb.y, QRb.z, QRb.w};
        float bi[4] = {QIb.x, QIb.y, QIb.z, QIb.w};
#pragma unroll
        for (int j = 0; j < 4; ++j) {
            const int k = k4 * 4 + j;
            float4 uw = s[k * 32 + ct];
            float4 vw = s[2048 + k * 32 + ct];
            Ra = f4fma(ar[j], uw, Ra); Ra = f4fma(ai[j], vw, Ra);
            Ia = f4fma(ai[j], uw, Ia); Ia = f4fma(-ar[j], vw, Ia);
            Rb = f4fma(br[j], uw, Rb); Rb = f4fma(bi[j], vw, Rb);
            Ib = f4fma(bi[j], uw, Ib); Ib = f4fma(-br[j], vw, Ib);
        }
    }
    const int cc = ct * 4;
    {
        float4 rin = *(const float4*)(re + (size_t)na * CC + cc);
        float4 iin = *(const float4*)(im + (size_t)na * CC + cc);
        float4 orr, oii;
        orr.x = rin.x + (Ra.x >= 0.f ? Ra.x : 0.f); oii.x = iin.x + (Ra.x >= 0.f ? Ia.x : 0.f);
        orr.y = rin.y + (Ra.y >= 0.f ? Ra.y : 0.f); oii.y = iin.y + (Ra.y >= 0.f ? Ia.y : 0.f);
        orr.z = rin.z + (Ra.z >= 0.f ? Ra.z : 0.f); oii.z = iin.z + (Ra.z >= 0.f ? Ia.z : 0.f);
        orr.w = rin.w + (Ra.w >= 0.f ? Ra.w : 0.f); oii.w = iin.w + (Ra.w >= 0.f ? Ia.w : 0.f);
        *(float4*)(out + (size_t)na * CC + cc)          = orr;
        *(float4*)(out + OUTOFF + (size_t)na * CC + cc) = oii;
    }
    {
        float4 rin = *(const float4*)(re + (size_t)nb * CC + cc);
        float4 iin = *(const float4*)(im + (size_t)nb * CC + cc);
        float4 orr, oii;
        orr.x = rin.x + (Rb.x >= 0.f ? Rb.x : 0.f); oii.x = iin.x + (Rb.x >= 0.f ? Ib.x : 0.f);
        orr.y = rin.y + (Rb.y >= 0.f ? Rb.y : 0.f); oii.y = iin.y + (Rb.y >= 0.f ? Ib.y : 0.f);
        orr.z = rin.z + (Rb.z >= 0.f ? Rb.z : 0.f); oii.z = iin.z + (Rb.z >= 0.f ? Ib.z : 0.f);
        orr.w = rin.w + (Rb.w >= 0.f ? Rb.w : 0.f); oii.w = iin.w + (Rb.w >= 0.f ? Ib.w : 0.f);
        *(float4*)(out + (size_t)nb * CC + cc)          = orr;
        *(float4*)(out + OUTOFF + (size_t)nb * CC + cc) = oii;
    }
}

extern "C" void kernel_launch(void* const* d_in, const int* in_sizes, int n_in,
                              void* d_out, int out_size, void* d_ws, size_t ws_size,
                              hipStream_t stream) {
    const float* re   = (const float*)d_in[0];
    const float* im   = (const float*)d_in[1];
    const float* Qr   = (const float*)d_in[2];
    const float* Qi   = (const float*)d_in[3];
    const float* Ritz = (const float*)d_in[4];
    const float* W    = (const float*)d_in[5];
    const int*   ldp  = (const int*)d_in[6];
    float* out = (float*)d_out;
    float* ws  = (float*)d_ws;

    float* part = ws;                          // NA * 16384 floats
    float* UVW  = ws + (size_t)NA * 16384;     // 16384 floats

    kA <<<NA,  512, 0, stream>>>(re, im, Qr, Qi, part);
    kRB<<<128, 256, 0, stream>>>(part, Ritz, ldp, W, UVW);
    kC <<<625, 256, 0, stream>>>(re, im, Qr, Qi, UVW, out);
}